// Round 1
// baseline (332.458 us; speedup 1.0000x reference)
//
#include <hip/hip_runtime.h>

#define NUM_NODES 2000
#define N_EDGES   32000
#define BT        192               // B*T = 16*12
#define F_INN     32
#define ROWS      (NUM_NODES * BT)  // 384000 rows of 32
#define NODE_F4   1536              // BT*F_IN/4 float4 per node

// ---- CSR build ----------------------------------------------------------

__global__ __launch_bounds__(256) void k_zero(int* deg, int* cursor) {
    int i = blockIdx.x * 256 + threadIdx.x;
    if (i < NUM_NODES) { deg[i] = 0; cursor[i] = 0; }
}

__global__ __launch_bounds__(256) void k_count(const int* __restrict__ src, int* deg) {
    int e = blockIdx.x * 256 + threadIdx.x;
    if (e < N_EDGES) atomicAdd(&deg[src[e]], 1);
}

__global__ __launch_bounds__(256) void k_scan(const int* __restrict__ deg, int* __restrict__ offs) {
    __shared__ int part[256];
    __shared__ int pre[257];
    int t = threadIdx.x;
    int base = t * 8;
    int s = 0;
#pragma unroll
    for (int i = 0; i < 8; i++) { int idx = base + i; if (idx < NUM_NODES) s += deg[idx]; }
    part[t] = s;
    __syncthreads();
    if (t == 0) {
        int r = 0;
        for (int i = 0; i < 256; i++) { pre[i] = r; r += part[i]; }
        pre[256] = r;
    }
    __syncthreads();
    int run = pre[t];
#pragma unroll
    for (int i = 0; i < 8; i++) {
        int idx = base + i;
        if (idx < NUM_NODES) { offs[idx] = run; run += deg[idx]; }
    }
    if (t == 0) offs[NUM_NODES] = pre[256];
}

__global__ __launch_bounds__(256) void k_scatter(const int* __restrict__ src, const int* __restrict__ dst,
                                                 const int* __restrict__ offs, int* cursor,
                                                 int* __restrict__ nbr) {
    int e = blockIdx.x * 256 + threadIdx.x;
    if (e < N_EDGES) {
        int s = src[e];
        int pos = atomicAdd(&cursor[s], 1);
        nbr[offs[s] + pos] = dst[e];
    }
}

// ---- y = x @ W (pre-relu to ws), out[...,0:32] = relu(y) ---------------

__global__ __launch_bounds__(256) void k_mm(const float* __restrict__ x, const float* __restrict__ w,
                                            float* __restrict__ y, float* __restrict__ out) {
    __shared__ float sW[1024];
    for (int i = threadIdx.x; i < 1024; i += 256) sW[i] = w[i];
    __syncthreads();
    size_t row = (size_t)blockIdx.x * 256 + threadIdx.x;  // < 384000 (exact)
    const float4* xr = (const float4*)(x + row * 32);
    float4 xv[8];
#pragma unroll
    for (int i = 0; i < 8; i++) xv[i] = xr[i];
    const float4* sW4 = (const float4*)sW;
    float4* y4 = (float4*)(y + row * 32);
    float4* o4 = (float4*)(out + row * 64);
#pragma unroll
    for (int c4 = 0; c4 < 8; c4++) {
        float4 a = make_float4(0.f, 0.f, 0.f, 0.f);
#pragma unroll
        for (int k = 0; k < 32; k++) {
            float xk = ((const float*)xv)[k];   // static index after unroll
            float4 wv = sW4[k * 8 + c4];
            a.x += xk * wv.x; a.y += xk * wv.y; a.z += xk * wv.z; a.w += xk * wv.w;
        }
        y4[c4] = a;
        o4[c4] = make_float4(fmaxf(a.x, 0.f), fmaxf(a.y, 0.f), fmaxf(a.z, 0.f), fmaxf(a.w, 0.f));
    }
}

// ---- gather-mean over neighbors, out[...,32:64] = relu(mean(y[nbr])) ---

__global__ __launch_bounds__(256) void k_gather(const float4* __restrict__ y4,
                                                const int* __restrict__ offs,
                                                const int* __restrict__ nbr,
                                                float* __restrict__ out) {
    int n = blockIdx.x;
    int t = threadIdx.x;
    int beg = offs[n];
    int end = offs[n + 1];
    float4 acc[6];
#pragma unroll
    for (int j = 0; j < 6; j++) acc[j] = make_float4(0.f, 0.f, 0.f, 0.f);
#pragma unroll 2
    for (int i = beg; i < end; i++) {
        int d = nbr[i];
        const float4* p = y4 + (size_t)d * NODE_F4 + t;
#pragma unroll
        for (int j = 0; j < 6; j++) {
            float4 v = p[j * 256];
            acc[j].x += v.x; acc[j].y += v.y; acc[j].z += v.z; acc[j].w += v.w;
        }
    }
    int cnt = end - beg;
    float inv = 1.0f / (float)(cnt > 1 ? cnt : 1);
#pragma unroll
    for (int j = 0; j < 6; j++) {
        int fi = j * 256 + t;          // float4 index in [0,1536)
        int r  = fi >> 3;              // row (bt) = fi*4/32
        int c  = (fi & 7) * 4;         // col within 32
        float4 v;
        v.x = fmaxf(acc[j].x * inv, 0.f);
        v.y = fmaxf(acc[j].y * inv, 0.f);
        v.z = fmaxf(acc[j].z * inv, 0.f);
        v.w = fmaxf(acc[j].w * inv, 0.f);
        float4* op = (float4*)(out + ((size_t)n * BT + r) * 64 + 32 + c);
        *op = v;
    }
}

extern "C" void kernel_launch(void* const* d_in, const int* in_sizes, int n_in,
                              void* d_out, int out_size, void* d_ws, size_t ws_size,
                              hipStream_t stream) {
    const float* x = (const float*)d_in[0];
    const float* w = (const float*)d_in[1];
    const int* esrc = (const int*)d_in[2];
    const int* edst = (const int*)d_in[3];
    float* out = (float*)d_out;

    // workspace layout
    float* y   = (float*)d_ws;                                   // 12,288,000 f32
    int* deg   = (int*)((char*)d_ws + (size_t)ROWS * 32 * 4);    // 2000
    int* offs  = deg + 2048;                                     // 2001
    int* cursor= offs + 2048;                                    // 2000
    int* nbr   = cursor + 2048;                                  // 32000

    k_zero<<<(NUM_NODES + 255) / 256, 256, 0, stream>>>(deg, cursor);
    k_count<<<(N_EDGES + 255) / 256, 256, 0, stream>>>(esrc, deg);
    k_scan<<<1, 256, 0, stream>>>(deg, offs);
    k_scatter<<<(N_EDGES + 255) / 256, 256, 0, stream>>>(esrc, edst, offs, cursor, nbr);
    k_mm<<<ROWS / 256, 256, 0, stream>>>(x, w, y, out);
    k_gather<<<NUM_NODES, 256, 0, stream>>>((const float4*)y, offs, nbr, out);
}

// Round 7
// 236.634 us; speedup vs baseline: 1.4049x; 1.4049x over previous
//
#include <hip/hip_runtime.h>

#define NUM_NODES 2000
#define N_EDGES   32000
#define BT        192               // B*T = 16*12
#define ROWS      (NUM_NODES * BT)  // 384000 rows of 32
#define NODE_F4   1536              // BT*F_IN/4 float4 per node
#define C4        64                // float4 per node per gather chunk (1 KB)
#define NCHUNK    24                // 1536 / 64
#define NB_PER_BLK 4                // nodes per gather block
#define NODEBLKS  (NUM_NODES / NB_PER_BLK)  // 500

// ---- CSR build ----------------------------------------------------------

__global__ __launch_bounds__(256) void k_zero(int* deg, int* cursor) {
    int i = blockIdx.x * 256 + threadIdx.x;
    if (i < NUM_NODES) { deg[i] = 0; cursor[i] = 0; }
}

__global__ __launch_bounds__(256) void k_count(const int* __restrict__ src, int* deg) {
    int e = blockIdx.x * 256 + threadIdx.x;
    if (e < N_EDGES) atomicAdd(&deg[src[e]], 1);
}

__global__ __launch_bounds__(256) void k_scan(const int* __restrict__ deg, int* __restrict__ offs) {
    __shared__ int part[256];
    __shared__ int pre[257];
    int t = threadIdx.x;
    int base = t * 8;
    int s = 0;
#pragma unroll
    for (int i = 0; i < 8; i++) { int idx = base + i; if (idx < NUM_NODES) s += deg[idx]; }
    part[t] = s;
    __syncthreads();
    if (t == 0) {
        int r = 0;
        for (int i = 0; i < 256; i++) { pre[i] = r; r += part[i]; }
        pre[256] = r;
    }
    __syncthreads();
    int run = pre[t];
#pragma unroll
    for (int i = 0; i < 8; i++) {
        int idx = base + i;
        if (idx < NUM_NODES) { offs[idx] = run; run += deg[idx]; }
    }
    if (t == 0) offs[NUM_NODES] = pre[256];
}

__global__ __launch_bounds__(256) void k_scatter(const int* __restrict__ src, const int* __restrict__ dst,
                                                 const int* __restrict__ offs, int* cursor,
                                                 int* __restrict__ nbr) {
    int e = blockIdx.x * 256 + threadIdx.x;
    if (e < N_EDGES) {
        int s = src[e];
        int pos = atomicAdd(&cursor[s], 1);
        nbr[offs[s] + pos] = dst[e];
    }
}

// ---- y = x @ W (pre-relu to ws), out[...,0:32] = relu(y) ---------------
// Block handles 64 rows (64x32 x-tile staged in LDS, padded stride 9 float4).
// Thread t computes output float4s o = t and o = t+256:
//   row = o>>3 (within block), c4 = o&7.
// y stores fully coalesced; out stores in 128B segments.

__global__ __launch_bounds__(256) void k_mm(const float4* __restrict__ x4, const float4* __restrict__ w4,
                                            float4* __restrict__ y4, float4* __restrict__ out4) {
    __shared__ float4 sW4[256];          // W: 32x32 floats, row k holds float4s k*8..k*8+7
    __shared__ float4 x_s4[64 * 9];      // 64 rows, 8 float4 each, stride 9 (pad)
    int t = threadIdx.x;
    sW4[t] = w4[t];
    size_t gbase = (size_t)blockIdx.x * 512;   // block's first x float4
#pragma unroll
    for (int g = 0; g < 2; g++) {
        int gi = t + g * 256;                  // 0..511
        float4 v = x4[gbase + gi];
        x_s4[(gi >> 3) * 9 + (gi & 7)] = v;
    }
    __syncthreads();

#pragma unroll
    for (int oo = 0; oo < 2; oo++) {
        int o  = t + oo * 256;     // 0..511
        int r  = o >> 3;           // row within block
        int c4 = o & 7;            // output float4 column
        float4 xr[8];
#pragma unroll
        for (int j = 0; j < 8; j++) xr[j] = x_s4[r * 9 + j];
        float4 a = make_float4(0.f, 0.f, 0.f, 0.f);
#pragma unroll
        for (int k = 0; k < 32; k++) {
            float xk = ((const float*)xr)[k];
            float4 wv = sW4[k * 8 + c4];
            a.x += xk * wv.x; a.y += xk * wv.y; a.z += xk * wv.z; a.w += xk * wv.w;
        }
        y4[gbase + o] = a;
        size_t grow = (size_t)blockIdx.x * 64 + r;
        out4[grow * 16 + c4] = make_float4(fmaxf(a.x, 0.f), fmaxf(a.y, 0.f),
                                           fmaxf(a.z, 0.f), fmaxf(a.w, 0.f));
    }
}

// ---- gather-mean over neighbors, out[...,32:64] = relu(mean(y[nbr])) ---
// Feature-chunked: chunk = 64 float4 (1 KB/node); slab = 2000 KB fits L2.
// blockIdx = chunk*NODEBLKS + nodeblock  (chunk-major => slab-resident L2).
// 256 threads = 4 groups of 64 lanes; group handles one node, lane = float4.

__global__ __launch_bounds__(256) void k_gather(const float4* __restrict__ y4,
                                                const int* __restrict__ offs,
                                                const int* __restrict__ nbr,
                                                float4* __restrict__ out4) {
    int chunk = blockIdx.x / NODEBLKS;
    int nb    = blockIdx.x - chunk * NODEBLKS;
    int g  = threadIdx.x >> 6;
    int tf = threadIdx.x & 63;
    int n  = nb * NB_PER_BLK + g;
    int beg = offs[n];
    int end = offs[n + 1];
    const float4* ybase = y4 + (size_t)chunk * C4 + tf;
    float4 a0 = make_float4(0.f, 0.f, 0.f, 0.f);
    float4 a1 = make_float4(0.f, 0.f, 0.f, 0.f);
    int i = beg;
    for (; i + 1 < end; i += 2) {
        int d0 = nbr[i];
        int d1 = nbr[i + 1];
        float4 v0 = ybase[(size_t)d0 * NODE_F4];
        float4 v1 = ybase[(size_t)d1 * NODE_F4];
        a0.x += v0.x; a0.y += v0.y; a0.z += v0.z; a0.w += v0.w;
        a1.x += v1.x; a1.y += v1.y; a1.z += v1.z; a1.w += v1.w;
    }
    if (i < end) {
        int d0 = nbr[i];
        float4 v0 = ybase[(size_t)d0 * NODE_F4];
        a0.x += v0.x; a0.y += v0.y; a0.z += v0.z; a0.w += v0.w;
    }
    int cnt = end - beg;
    float inv = 1.0f / (float)(cnt > 1 ? cnt : 1);
    float4 v;
    v.x = fmaxf((a0.x + a1.x) * inv, 0.f);
    v.y = fmaxf((a0.y + a1.y) * inv, 0.f);
    v.z = fmaxf((a0.z + a1.z) * inv, 0.f);
    v.w = fmaxf((a0.w + a1.w) * inv, 0.f);
    int fi = chunk * C4 + tf;      // float4 index within node's 1536
    int r  = fi >> 3;              // bt row
    int c4 = fi & 7;               // float4 within 32-float half
    out4[((size_t)n * BT + r) * 16 + 8 + c4] = v;
}

extern "C" void kernel_launch(void* const* d_in, const int* in_sizes, int n_in,
                              void* d_out, int out_size, void* d_ws, size_t ws_size,
                              hipStream_t stream) {
    const float* x = (const float*)d_in[0];
    const float* w = (const float*)d_in[1];
    const int* esrc = (const int*)d_in[2];
    const int* edst = (const int*)d_in[3];
    float* out = (float*)d_out;

    // workspace layout
    float* y    = (float*)d_ws;                                   // 12,288,000 f32
    int* deg    = (int*)((char*)d_ws + (size_t)ROWS * 32 * 4);    // 2000
    int* offs   = deg + 2048;                                     // 2001
    int* cursor = offs + 2048;                                    // 2000
    int* nbr    = cursor + 2048;                                  // 32000

    k_zero<<<(NUM_NODES + 255) / 256, 256, 0, stream>>>(deg, cursor);
    k_count<<<(N_EDGES + 255) / 256, 256, 0, stream>>>(esrc, deg);
    k_scan<<<1, 256, 0, stream>>>(deg, offs);
    k_scatter<<<(N_EDGES + 255) / 256, 256, 0, stream>>>(esrc, edst, offs, cursor, nbr);
    k_mm<<<ROWS / 64, 256, 0, stream>>>((const float4*)x, (const float4*)w,
                                        (float4*)y, (float4*)out);
    k_gather<<<NCHUNK * NODEBLKS, 256, 0, stream>>>((const float4*)y, offs, nbr,
                                                    (float4*)out);
}

// Round 13
// 206.654 us; speedup vs baseline: 1.6088x; 1.1451x over previous
//
#include <hip/hip_runtime.h>

#define NUM_NODES 2000
#define N_EDGES   32000
#define BT        192               // B*T = 16*12
#define ROWS      (NUM_NODES * BT)  // 384000 rows of 32
#define NODE_F4   1536              // BT*F_IN/4 float4 per node
#define C4        64                // float4 per node per gather chunk (1 KB)
#define NCHUNK    24                // 1536 / 64
#define NB_PER_BLK 4                // nodes per gather block
#define NODEBLKS  (NUM_NODES / NB_PER_BLK)  // 500
#define NXCD      8
#define CHUNKS_PER_XCD (NCHUNK / NXCD)      // 3

// ---- CSR build (4-kernel chain — proven correct in R1/R7) --------------

__global__ __launch_bounds__(256) void k_zero(int* deg, int* cursor) {
    int i = blockIdx.x * 256 + threadIdx.x;
    if (i < NUM_NODES) { deg[i] = 0; cursor[i] = 0; }
}

__global__ __launch_bounds__(256) void k_count(const int* __restrict__ src, int* deg) {
    int e = blockIdx.x * 256 + threadIdx.x;
    if (e < N_EDGES) atomicAdd(&deg[src[e]], 1);
}

__global__ __launch_bounds__(256) void k_scan(const int* __restrict__ deg, int* __restrict__ offs) {
    __shared__ int part[256];
    __shared__ int pre[257];
    int t = threadIdx.x;
    int base = t * 8;
    int s = 0;
#pragma unroll
    for (int i = 0; i < 8; i++) { int idx = base + i; if (idx < NUM_NODES) s += deg[idx]; }
    part[t] = s;
    __syncthreads();
    if (t == 0) {
        int r = 0;
        for (int i = 0; i < 256; i++) { pre[i] = r; r += part[i]; }
        pre[256] = r;
    }
    __syncthreads();
    int run = pre[t];
#pragma unroll
    for (int i = 0; i < 8; i++) {
        int idx = base + i;
        if (idx < NUM_NODES) { offs[idx] = run; run += deg[idx]; }
    }
    if (t == 0) offs[NUM_NODES] = pre[256];
}

__global__ __launch_bounds__(256) void k_scatter(const int* __restrict__ src, const int* __restrict__ dst,
                                                 const int* __restrict__ offs, int* cursor,
                                                 int* __restrict__ nbr) {
    int e = blockIdx.x * 256 + threadIdx.x;
    if (e < N_EDGES) {
        int s = src[e];
        int pos = atomicAdd(&cursor[s], 1);
        nbr[offs[s] + pos] = dst[e];
    }
}

// ---- y = x @ W (pre-relu to ws), out[...,0:32] = relu(y) ---------------

__global__ __launch_bounds__(256) void k_mm(const float4* __restrict__ x4, const float4* __restrict__ w4,
                                            float4* __restrict__ y4, float4* __restrict__ out4) {
    __shared__ float4 sW4[256];          // W: 32x32 floats, row k holds float4s k*8..k*8+7
    __shared__ float4 x_s4[64 * 9];      // 64 rows, 8 float4 each, stride 9 (pad)
    int t = threadIdx.x;
    sW4[t] = w4[t];
    size_t gbase = (size_t)blockIdx.x * 512;   // block's first x float4
#pragma unroll
    for (int g = 0; g < 2; g++) {
        int gi = t + g * 256;                  // 0..511
        float4 v = x4[gbase + gi];
        x_s4[(gi >> 3) * 9 + (gi & 7)] = v;
    }
    __syncthreads();

#pragma unroll
    for (int oo = 0; oo < 2; oo++) {
        int o  = t + oo * 256;     // 0..511
        int r  = o >> 3;           // row within block
        int c4 = o & 7;            // output float4 column
        float4 xr[8];
#pragma unroll
        for (int j = 0; j < 8; j++) xr[j] = x_s4[r * 9 + j];
        float4 a = make_float4(0.f, 0.f, 0.f, 0.f);
#pragma unroll
        for (int k = 0; k < 32; k++) {
            float xk = ((const float*)xr)[k];
            float4 wv = sW4[k * 8 + c4];
            a.x += xk * wv.x; a.y += xk * wv.y; a.z += xk * wv.z; a.w += xk * wv.w;
        }
        y4[gbase + o] = a;
        size_t grow = (size_t)blockIdx.x * 64 + r;
        out4[grow * 16 + c4] = make_float4(fmaxf(a.x, 0.f), fmaxf(a.y, 0.f),
                                           fmaxf(a.z, 0.f), fmaxf(a.w, 0.f));
    }
}

// ---- gather-mean over neighbors, out[...,32:64] = relu(mean(y[nbr])) ---
// XCD-affinity: dispatch round-robins blockIdx across the 8 XCDs, so
// xcd = blockIdx&7. Each XCD owns 3 whole chunks -> its 2 MB slab is
// fetched from HBM once and stays resident in that XCD's private L2.

__global__ __launch_bounds__(256) void k_gather(const float4* __restrict__ y4,
                                                const int* __restrict__ offs,
                                                const int* __restrict__ nbr,
                                                float4* __restrict__ out4) {
    int b   = blockIdx.x;
    int xcd = b & 7;
    int j   = b >> 3;                  // 0..1499
    int cix = j / NODEBLKS;            // 0..2
    int nb  = j - cix * NODEBLKS;      // 0..499
    int chunk = xcd * CHUNKS_PER_XCD + cix;

    int g  = threadIdx.x >> 6;
    int tf = threadIdx.x & 63;
    int n  = nb * NB_PER_BLK + g;
    int beg = offs[n];
    int end = offs[n + 1];
    const float4* ybase = y4 + (size_t)chunk * C4 + tf;
    float4 a0 = make_float4(0.f, 0.f, 0.f, 0.f);
    float4 a1 = make_float4(0.f, 0.f, 0.f, 0.f);
    int i = beg;
    for (; i + 1 < end; i += 2) {
        int d0 = nbr[i];
        int d1 = nbr[i + 1];
        float4 v0 = ybase[(size_t)d0 * NODE_F4];
        float4 v1 = ybase[(size_t)d1 * NODE_F4];
        a0.x += v0.x; a0.y += v0.y; a0.z += v0.z; a0.w += v0.w;
        a1.x += v1.x; a1.y += v1.y; a1.z += v1.z; a1.w += v1.w;
    }
    if (i < end) {
        int d0 = nbr[i];
        float4 v0 = ybase[(size_t)d0 * NODE_F4];
        a0.x += v0.x; a0.y += v0.y; a0.z += v0.z; a0.w += v0.w;
    }
    int cnt = end - beg;
    float inv = 1.0f / (float)(cnt > 1 ? cnt : 1);
    float4 v;
    v.x = fmaxf((a0.x + a1.x) * inv, 0.f);
    v.y = fmaxf((a0.y + a1.y) * inv, 0.f);
    v.z = fmaxf((a0.z + a1.z) * inv, 0.f);
    v.w = fmaxf((a0.w + a1.w) * inv, 0.f);
    int fi = chunk * C4 + tf;      // float4 index within node's 1536
    int r  = fi >> 3;              // bt row
    int c4 = fi & 7;               // float4 within 32-float half
    out4[((size_t)n * BT + r) * 16 + 8 + c4] = v;
}

extern "C" void kernel_launch(void* const* d_in, const int* in_sizes, int n_in,
                              void* d_out, int out_size, void* d_ws, size_t ws_size,
                              hipStream_t stream) {
    const float* x = (const float*)d_in[0];
    const float* w = (const float*)d_in[1];
    const int* esrc = (const int*)d_in[2];
    const int* edst = (const int*)d_in[3];
    float* out = (float*)d_out;

    // workspace layout
    float* y    = (float*)d_ws;                                   // 12,288,000 f32
    int* deg    = (int*)((char*)d_ws + (size_t)ROWS * 32 * 4);    // 2000
    int* offs   = deg + 2048;                                     // 2001
    int* cursor = offs + 2048;                                    // 2000
    int* nbr    = cursor + 2048;                                  // 32000

    k_zero<<<(NUM_NODES + 255) / 256, 256, 0, stream>>>(deg, cursor);
    k_count<<<(N_EDGES + 255) / 256, 256, 0, stream>>>(esrc, deg);
    k_scan<<<1, 256, 0, stream>>>(deg, offs);
    k_scatter<<<(N_EDGES + 255) / 256, 256, 0, stream>>>(esrc, edst, offs, cursor, nbr);
    k_mm<<<ROWS / 64, 256, 0, stream>>>((const float4*)x, (const float4*)w,
                                        (float4*)y, (float4*)out);
    k_gather<<<NCHUNK * NODEBLKS, 256, 0, stream>>>((const float4*)y, offs, nbr,
                                                    (float4*)out);
}